// Round 5
// baseline (259.563 us; speedup 1.0000x reference)
//
#include <hip/hip_runtime.h>
#include <hip/hip_bf16.h>

#define RD 64
#define UD 64
#define VD 64
#define HD 128
#define XD 64
#define NB 8
#define SITES 1024

typedef float f32x4 __attribute__((ext_vector_type(4)));
typedef float f32x2 __attribute__((ext_vector_type(2)));
typedef __bf16 bf16x4 __attribute__((ext_vector_type(4)));
typedef __bf16 bf16x8 __attribute__((ext_vector_type(8)));
typedef unsigned int u32x4 __attribute__((ext_vector_type(4)));
typedef unsigned short u16;
typedef unsigned short u16x4 __attribute__((ext_vector_type(4)));

// Raw workgroup barrier WITHOUT the vmcnt(0) drain __syncthreads carries.
// 0xC07F = lgkmcnt(0), vmcnt=63 (open), expcnt=7 (open) on gfx9-lineage.
__device__ __forceinline__ void lds_barrier() {
  __builtin_amdgcn_s_waitcnt(0xC07F);
  __builtin_amdgcn_s_barrier();
}

// ---------------- kprep: all three input transforms in one launch ----------------
// b < 256   : w2 [x][r][h] fp32 -> w2t bf16 [r][x][h]
// b < 384   : r  [n][s][r] fp32 -> rt fp32 [n][r][s]
// else      : u  [n][r][u][v] fp32 -> ut fp32 [r][u][v][n]   (2048 blocks)
__global__ void kprep(const float* __restrict__ w2, u16* __restrict__ w2t,
                      const float* __restrict__ r, float* __restrict__ rt,
                      const float* __restrict__ u, float* __restrict__ ut) {
  __shared__ float tl[64][68];
  int b = blockIdx.x;
  int t = threadIdx.x;
  if (b < 256) {
    int rr = b >> 2, qq = b & 3;
    for (int i = 0; i < 8; ++i) {
      int idx = qq * 2048 + i * 256 + t;   // (x,h)
      int x = idx >> 7, h = idx & 127;
      float val = w2[((size_t)x * RD + rr) * HD + h];
      __hip_bfloat16 hv = __float2bfloat16(val);
      w2t[((size_t)rr * XD + x) * HD + h] = *(u16*)&hv;
    }
  } else if (b < 384) {
    int bb = b - 256;
    int n = bb >> 4, sb = (bb & 15) * 64;
    for (int i = 0; i < 4; ++i) {
      int flat = i * 256 + t;
      int s = flat >> 4, ch = flat & 15;
      f32x4 d = *(const f32x4*)(r + ((size_t)(n * SITES + sb + s) * RD + ch * 4));
      *(f32x4*)&tl[s][ch * 4] = d;
    }
    __syncthreads();
    for (int i = 0; i < 4; ++i) {
      int flat = i * 256 + t;
      int rr = flat >> 4, ch = flat & 15;
      f32x4 o;
      o.x = tl[ch * 4 + 0][rr];
      o.y = tl[ch * 4 + 1][rr];
      o.z = tl[ch * 4 + 2][rr];
      o.w = tl[ch * 4 + 3][rr];
      *(f32x4*)(rt + ((size_t)(n * RD + rr) * SITES + sb + ch * 4)) = o;
    }
  } else {
    int f = (b - 384) * 256 + t;        // 524288 f32x4 units of ut
    int nh = f & 1, v = (f >> 1) & 63, uu = (f >> 7) & 63, rr = f >> 13;
    f32x4 o;
#pragma unroll
    for (int k = 0; k < 4; ++k)
      o[k] = u[(((size_t)(nh * 4 + k) * RD + rr) * UD + uu) * VD + v];
    *(f32x4*)(ut + (size_t)f * 4) = o;
  }
}

// ---------------- k_a_full v5: full-page contiguous w1 bursts -------------------
// R4 post-mortem: v2/v3/v4 all pinned at ~2.8 TB/s regardless of segment size or
// occupancy.  Invariant: per uu each wave read 1 KB as 128-256 B pieces at 512-B
// stride inside a 2-4 KB window, then jumped 32 KB -> ~45% DRAM page utilization.
// v5: grid 256 = rr(64) x vq(4); block owns 16 COMPLETE v-rows (all 128 h).
// Lane L: v = vq*16 + L/16, h-chunk = (L%16)*8 -> 32 B contiguous/lane; per uu the
// wave reads 2 KB contiguous and the BLOCK reads one contiguous 8-KB run (full
// pages consumed per activation).  Zero redundancy on w1 grid-wide.  acc[8n][8h]
// (64 VGPR) + PF=8 ring (static indices: unroll-8 main loop of 56 + unrolled
// tails) at launch_bounds(256,1) -> no spill, 24 loads/thread in flight.
// Numerics: same sequential uu=0..63 fp32 accumulation per (v,h), single bf16
// round -> bit-identical at.
#define PF 8
__global__ __launch_bounds__(256, 1) void k_a_full(const float* __restrict__ w1,
                                                   const float* __restrict__ ut,
                                                   u16* __restrict__ at) {
  __shared__ float tile[8 * 128 * 17];  // 68 KB: [n][h][v_local(16)+pad]
  int b = blockIdx.x;                   // 256 = rr(64) x vq(4)
  int rr = b >> 2, vq = b & 3;
  int t = threadIdx.x;                  // 256
  int vl = t >> 4;                      // v-local (16)
  int hs = t & 15;                      // 16 h-strips x 8 h
  int v = vq * 16 + vl;
  int h0 = hs * 8;
  const float* w1p = w1 + ((size_t)rr * UD * VD + v) * HD + h0;   // + uu*8192
  const float* up  = ut + ((size_t)rr * UD * VD + v) * NB;        // + uu*512

  f32x4 accA[8], accB[8];               // [n] x (h0..h0+3, h0+4..h0+7)
#pragma unroll
  for (int n = 0; n < 8; ++n) { accA[n] = (f32x4)0.f; accB[n] = (f32x4)0.f; }

  f32x4 wa[PF], wb[PF], ua[PF], ub[PF];
#pragma unroll
  for (int p = 0; p < PF; ++p) {
    wa[p] = *(const f32x4*)(w1p + (size_t)p * 8192);
    wb[p] = *(const f32x4*)(w1p + (size_t)p * 8192 + 4);
    ua[p] = *(const f32x4*)(up + (size_t)p * 512);
    ub[p] = *(const f32x4*)(up + (size_t)p * 512 + 4);
  }

#define KA_CONSUME(P)                                                     \
  {                                                                       \
    f32x4 w0 = wa[P], w1v = wb[P], u0 = ua[P], u1 = ub[P];                \
    accA[0] += w0 * u0.x; accB[0] += w1v * u0.x;                          \
    accA[1] += w0 * u0.y; accB[1] += w1v * u0.y;                          \
    accA[2] += w0 * u0.z; accB[2] += w1v * u0.z;                          \
    accA[3] += w0 * u0.w; accB[3] += w1v * u0.w;                          \
    accA[4] += w0 * u1.x; accB[4] += w1v * u1.x;                          \
    accA[5] += w0 * u1.y; accB[5] += w1v * u1.y;                          \
    accA[6] += w0 * u1.z; accB[6] += w1v * u1.z;                          \
    accA[7] += w0 * u1.w; accB[7] += w1v * u1.w;                          \
  }

#pragma unroll 8
  for (int uu = 0; uu < 56; ++uu) {
    const int p = uu & 7;               // static under unroll-8
    f32x4 w0 = wa[p], w1v = wb[p], u0 = ua[p], u1 = ub[p];
    wa[p] = *(const f32x4*)(w1p + (size_t)(uu + 8) * 8192);
    wb[p] = *(const f32x4*)(w1p + (size_t)(uu + 8) * 8192 + 4);
    ua[p] = *(const f32x4*)(up + (size_t)(uu + 8) * 512);
    ub[p] = *(const f32x4*)(up + (size_t)(uu + 8) * 512 + 4);
    accA[0] += w0 * u0.x; accB[0] += w1v * u0.x;
    accA[1] += w0 * u0.y; accB[1] += w1v * u0.y;
    accA[2] += w0 * u0.z; accB[2] += w1v * u0.z;
    accA[3] += w0 * u0.w; accB[3] += w1v * u0.w;
    accA[4] += w0 * u1.x; accB[4] += w1v * u1.x;
    accA[5] += w0 * u1.y; accB[5] += w1v * u1.y;
    accA[6] += w0 * u1.z; accB[6] += w1v * u1.z;
    accA[7] += w0 * u1.w; accB[7] += w1v * u1.w;
  }
  // tail: consume uu = 56..63 (ring slots 0..7), no refills
  KA_CONSUME(0) KA_CONSUME(1) KA_CONSUME(2) KA_CONSUME(3)
  KA_CONSUME(4) KA_CONSUME(5) KA_CONSUME(6) KA_CONSUME(7)
#undef KA_CONSUME

  // ---- LDS transpose: tile[n][h][v_local], row stride 17 floats ----
#pragma unroll
  for (int n = 0; n < 8; ++n)
#pragma unroll
    for (int j = 0; j < 4; ++j) {
      tile[((n << 7) + h0 + j) * 17 + vl] = accA[n][j];
      tile[((n << 7) + h0 + 4 + j) * 17 + vl] = accB[n][j];
    }
  __syncthreads();

  // ---- bf16 store: 4096 u16x4 units (n(8), h(128), c4(4)), 16/thread.
  // 4 consecutive lanes cover the block's 16 v = 32-B runs (at is MALL-hot
  // for k_main, so the halved run length is acceptable).
#pragma unroll
  for (int k = 0; k < 16; ++k) {
    int flat = k * 256 + t;
    int c4 = flat & 3, h = (flat >> 2) & 127, n = flat >> 9;
    const float* src = &tile[((n << 7) + h) * 17 + c4 * 4];
    u16x4 o;
#pragma unroll
    for (int j = 0; j < 4; ++j) {
      __hip_bfloat16 hv = __float2bfloat16(src[j]);
      o[j] = *(u16*)&hv;
    }
    *(u16x4*)(at + (((size_t)n * RD + rr) * HD + h) * VD + vq * 16 + c4 * 4) = o;
  }
}

// ---------------- k_main: fused GEMM1 (P^T = A_r^T * V^T) + relu*r + GEMM2 ------
// R6 known-good structure (512 blocks x 256 thr, 64 KB double-buffered swizzled
// Plds, ONE lds_barrier per rr).  Unchanged.
__global__ __launch_bounds__(256, 1) void k_main(const float* __restrict__ vin,
                                                 const u16* __restrict__ at,
                                                 const u16* __restrict__ w2t,
                                                 const float* __restrict__ rt,
                                                 float* __restrict__ pbuf) {
  __shared__ __align__(16) char Plds[2 * 128 * 256];   // 64 KB exactly
  int b = blockIdx.x;                 // 512 = n(8) x stile(8) x rchunk(8)
  int rc = b & 7, st = (b >> 3) & 7, n = b >> 6;
  int t = threadIdx.x;
  int w = t >> 6, L = t & 63, q = L >> 4, c = L & 15;
  int g2m = w >> 1, g2x = w & 1;      // GEMM2: s-half x x-half

  // V fragments (B-operand of GEMM1), register-resident for all r-steps
  bf16x8 vf[4][2];
#pragma unroll
  for (int nt = 0; nt < 4; ++nt)
#pragma unroll
    for (int ks = 0; ks < 2; ++ks) {
      int s = (w & 1) * 64 + nt * 16 + c;
      const float* vp = vin + ((size_t)(n * SITES + st * 128 + s) * VD + ks * 32 + q * 8);
      f32x4 a0 = *(const f32x4*)vp;
      f32x4 a1 = *(const f32x4*)(vp + 4);
      bf16x8 f;
      f[0] = (__bf16)a0.x; f[1] = (__bf16)a0.y; f[2] = (__bf16)a0.z; f[3] = (__bf16)a0.w;
      f[4] = (__bf16)a1.x; f[5] = (__bf16)a1.y; f[6] = (__bf16)a1.z; f[7] = (__bf16)a1.w;
      vf[nt][ks] = f;
    }

  f32x4 o[4][2];
#pragma unroll
  for (int i = 0; i < 4; i++)
#pragma unroll
    for (int j = 0; j < 2; j++) o[i][j] = (f32x4)0.f;

  int g1m = w >> 1, g1n = w & 1;      // GEMM1: h-half x s-half
  for (int rr = rc * 8; rr < rc * 8 + 8; ++rr) {
    const u16* abase = at + (size_t)(n * RD + rr) * 8192;   // [h][v] plain

    // A-frags direct from global: 16B = 8 consecutive v at fixed h
    bf16x8 af[4][2];
#pragma unroll
    for (int mt = 0; mt < 4; ++mt)
#pragma unroll
      for (int ks = 0; ks < 2; ++ks) {
        int h = g1m * 64 + mt * 16 + c;
        int vb = ks * 4 + q;
        af[mt][ks] = *(const bf16x8*)(abase + (size_t)h * VD + vb * 8);
      }
    // W2r b-frags from global (L2-hot)
    u32x4 wraw[2][4];
#pragma unroll
    for (int xt = 0; xt < 2; ++xt)
#pragma unroll
      for (int k2 = 0; k2 < 4; ++k2) {
        int xg = g2x * 32 + xt * 16 + c;
        wraw[xt][k2] = *(const u32x4*)((const char*)w2t +
                        (((size_t)(rr * XD + xg)) * HD + k2 * 32 + q * 8) * 2);
      }
    float rsc[4];
#pragma unroll
    for (int nt = 0; nt < 4; ++nt)
      rsc[nt] = rt[(size_t)(n * RD + rr) * SITES + st * 128 + g1n * 64 + nt * 16 + c];

    // GEMM1: D = A_r^T (m=h) x V^T (n=s), K=v=64
    f32x4 cc[4][4];
#pragma unroll
    for (int mt = 0; mt < 4; ++mt)
#pragma unroll
      for (int nt = 0; nt < 4; ++nt) cc[mt][nt] = (f32x4)0.f;
#pragma unroll
    for (int ks = 0; ks < 2; ++ks)
#pragma unroll
      for (int mt = 0; mt < 4; ++mt)
#pragma unroll
        for (int nt = 0; nt < 4; ++nt)
          cc[mt][nt] = __builtin_amdgcn_mfma_f32_16x16x32_bf16(af[mt][ks], vf[nt][ks],
                                                               cc[mt][nt], 0, 0, 0);

    // relu, scale by r, pack to Plds buf rr&1, XOR-swizzled 16B blocks:
    // element (s, h-block hb8=h>>3) stored at block (hb8 ^ (s&15)) within row s.
    char* PB = Plds + (rr & 1) * 32768;
#pragma unroll
    for (int mt = 0; mt < 4; ++mt)
#pragma unroll
      for (int nt = 0; nt < 4; ++nt) {
        float sc = rsc[nt];
        bf16x4 pv;
#pragma unroll
        for (int jj = 0; jj < 4; ++jj) {
          float x = cc[mt][nt][jj];
          x = x > 0.f ? x : 0.f;
          pv[jj] = (__bf16)(x * sc);
        }
        int s = g1n * 64 + nt * 16 + c;          // s&15 == c
        int blk = g1m * 8 + mt * 2 + (q >> 1);   // = h>>3
        *(bf16x4*)(PB + (size_t)s * 256 + (size_t)((blk ^ c) * 16 + (q & 1) * 8)) = pv;
      }
    lds_barrier();   // lgkm-only barrier — no vmcnt(0) drain per rr

    // GEMM2: O[s,x] += P (m=s, A-op) x W2r^T (n=x), K=h=128
#pragma unroll
    for (int k2 = 0; k2 < 4; ++k2) {
      bf16x8 wf0 = __builtin_bit_cast(bf16x8, wraw[0][k2]);
      bf16x8 wf1 = __builtin_bit_cast(bf16x8, wraw[1][k2]);
#pragma unroll
      for (int mt = 0; mt < 4; ++mt) {
        int s = g2m * 64 + mt * 16 + c;          // s&15 == c
        int blk = k2 * 4 + q;                    // = h>>3
        bf16x8 pf = *(const bf16x8*)(PB + (size_t)s * 256 + (size_t)((blk ^ c) * 16));
        o[mt][0] = __builtin_amdgcn_mfma_f32_16x16x32_bf16(pf, wf0, o[mt][0], 0, 0, 0);
        o[mt][1] = __builtin_amdgcn_mfma_f32_16x16x32_bf16(pf, wf1, o[mt][1], 0, 0, 0);
      }
    }
  }
  // epilogue: plain vector stores to partial buffer pbuf[rc][n][st][x][s]
#pragma unroll
  for (int mt = 0; mt < 4; ++mt)
#pragma unroll
    for (int xt = 0; xt < 2; ++xt) {
      int s0 = g2m * 64 + mt * 16 + q * 4;
      int x = g2x * 32 + xt * 16 + c;
      size_t off = ((((size_t)rc * NB + n) * 8 + st) * XD + x) * 128 + s0;
      *(f32x4*)(pbuf + off) = o[mt][xt];
    }
}

// ---------------- k_reduce: out[n][s][x] = sum_rc pbuf[rc][n][st][x][s] ---------
__global__ __launch_bounds__(256) void k_reduce(const float* __restrict__ pbuf,
                                                float* __restrict__ out) {
  __shared__ float tile[128][17];
  int b = blockIdx.x;                 // 256 = n(8) x st(8) x xq(4)
  int n = b >> 5, st = (b >> 2) & 7, xq = b & 3;
  int t = threadIdx.x;
  int sq = t & 31, xl = t >> 5;       // phase-1: s-quad, x-lane (8)
#pragma unroll
  for (int p = 0; p < 2; ++p) {
    int x = xq * 16 + p * 8 + xl;
    f32x4 sum = (f32x4)0.f;
#pragma unroll
    for (int rcc = 0; rcc < 8; ++rcc) {
      size_t off = ((((size_t)rcc * NB + n) * 8 + st) * XD + x) * 128 + sq * 4;
      f32x4 d = *(const f32x4*)(pbuf + off);
      sum.x += d.x; sum.y += d.y; sum.z += d.z; sum.w += d.w;
    }
#pragma unroll
    for (int k = 0; k < 4; ++k) tile[sq * 4 + k][p * 8 + xl] = sum[k];
  }
  __syncthreads();
  // phase-2: coalesced out write, f32x4 along x
#pragma unroll
  for (int k = 0; k < 2; ++k) {
    int flat = k * 256 + t;
    int s = flat >> 2, c4 = flat & 3;
    f32x4 o;
#pragma unroll
    for (int j = 0; j < 4; ++j) o[j] = tile[s][c4 * 4 + j];
    *(f32x4*)(out + ((size_t)(n * SITES + st * 128 + s) * XD + xq * 16 + c4 * 4)) = o;
  }
}

extern "C" void kernel_launch(void* const* d_in, const int* in_sizes, int n_in,
                              void* d_out, int out_size, void* d_ws, size_t ws_size,
                              hipStream_t stream) {
  const float* r  = (const float*)d_in[0];
  const float* u  = (const float*)d_in[1];
  const float* v  = (const float*)d_in[2];
  const float* w1 = (const float*)d_in[3];
  const float* w2 = (const float*)d_in[4];
  float* out = (float*)d_out;
  char* ws = (char*)d_ws;
  u16* at     = (u16*)(ws);                         // 8 MB  bf16 a, [n][r][h][v]
  u16* w2t    = (u16*)(ws + ((size_t)8 << 20));     // 1 MB  bf16 w2 [r][x][h]
  float* rt   = (float*)(ws + ((size_t)9 << 20));   // 2 MB  fp32 r [n][r][s]
  float* ut   = (float*)(ws + ((size_t)11 << 20));  // 8 MB  fp32 u [r][u][v][n]
  float* pbuf = (float*)(ws + ((size_t)19 << 20));  // 16 MB fp32 out-partials [rc][n][st][x][s]

  hipLaunchKernelGGL(kprep, dim3(2432), dim3(256), 0, stream, w2, w2t, r, rt, u, ut);
  hipLaunchKernelGGL(k_a_full, dim3(256), dim3(256), 0, stream, w1, ut, at);
  hipLaunchKernelGGL(k_main, dim3(512), dim3(256), 0, stream, v, at, w2t, rt, pbuf);
  hipLaunchKernelGGL(k_reduce, dim3(256), dim3(256), 0, stream, pbuf, out);
}